// Round 1
// baseline (6749.557 us; speedup 1.0000x reference)
//
#include <hip/hip_runtime.h>
#include <math.h>

// Problem dims
#define BB 64
#define TT 512
#define DD 256
#define HH 1024
#define GG 4096  // 4*H

typedef __bf16 bf16x8 __attribute__((ext_vector_type(8)));
typedef float floatx4 __attribute__((ext_vector_type(4)));

// ---------------- fp32 -> bf16 conversion (weights) ----------------
__global__ void cvt_bf16_kernel(const float* __restrict__ src,
                                __bf16* __restrict__ dst, int n) {
    int i = (blockIdx.x * blockDim.x + threadIdx.x) * 8;
    if (i >= n) return;
    float4 a = *(const float4*)(src + i);
    float4 b = *(const float4*)(src + i + 4);
    bf16x8 v;
    v[0] = (__bf16)a.x; v[1] = (__bf16)a.y; v[2] = (__bf16)a.z; v[3] = (__bf16)a.w;
    v[4] = (__bf16)b.x; v[5] = (__bf16)b.y; v[6] = (__bf16)b.z; v[7] = (__bf16)b.w;
    *(bf16x8*)(dst + i) = v;
}

// ---------------- init: combined bias, zero cell state ----------------
__global__ void init_misc_kernel(const float* __restrict__ bx,
                                 const float* __restrict__ bh,
                                 float* __restrict__ bc,
                                 float* __restrict__ cst) {
    int i = blockIdx.x * blockDim.x + threadIdx.x;
    if (i < GG) bc[i] = bx[i] + bh[i];
    if (i < BB * HH) cst[i] = 0.0f;
}

// ---------------- one LSTM timestep ----------------
// grid: 256 blocks (j-tile of 4), 256 threads (4 waves).
// Block computes gates[64 b][16 packed rows] where packed row n = gate*4+jj,
// gate in {i,f,g,o}, j = blockIdx.x*4 + jj.  K = 256 (x part) + 1024 (h part).
__global__ __launch_bounds__(256) void lstm_step_kernel(
    const float* __restrict__ x,      // (B,T,D) fp32
    const __bf16* __restrict__ Wxb,   // (4096,256) bf16
    const __bf16* __restrict__ Whb,   // (4096,1024) bf16
    const float* __restrict__ bc,     // (4096) combined bias
    float* __restrict__ cst,          // (B,H) fp32 cell state
    float* __restrict__ hs,           // (B,T,H) fp32 raw h  (d_out hidden region)
    __bf16* __restrict__ hping,       // 2 x (B*H) bf16 ping-pong h
    int t) {
    // 16 gathered gate rows x 1280 K, +8 pad per row for LDS bank spread
    __shared__ __bf16 W_s[16][1288];
    __shared__ float gate_s[64][17];

    const int tid = threadIdx.x;
    const int j0 = blockIdx.x * 4;

    // Stage [Wx | Wh] rows for the 16 packed gate rows. 16 rows * 160 chunks(8 bf16).
    for (int ch = tid; ch < 2560; ch += 256) {
        int r = ch / 160;
        int pos = ch - r * 160;
        int k = pos * 8;
        int gate = r >> 2;
        int jj = r & 3;
        int gr = gate * HH + j0 + jj;
        const __bf16* src = (k < DD) ? (Wxb + (size_t)gr * DD + k)
                                     : (Whb + (size_t)gr * HH + (k - DD));
        *(uint4*)(&W_s[r][k]) = *(const uint4*)src;
    }
    __syncthreads();

    const int wave = tid >> 6;
    const int lane = tid & 63;
    const int ln = lane & 15;   // A row (b within wave tile) AND B row (packed gate)
    const int q = lane >> 4;    // k-quad
    const int brow = wave * 16 + ln;

    floatx4 acc = {0.f, 0.f, 0.f, 0.f};

    // x part: K = 0..255 (convert fp32 -> bf16 in-lane)
    {
        const float* xrow = x + ((size_t)brow * TT + t) * DD;
#pragma unroll
        for (int k0 = 0; k0 < DD; k0 += 32) {
            int ka = k0 + q * 8;
            float4 f0 = *(const float4*)(xrow + ka);
            float4 f1 = *(const float4*)(xrow + ka + 4);
            bf16x8 av;
            av[0] = (__bf16)f0.x; av[1] = (__bf16)f0.y;
            av[2] = (__bf16)f0.z; av[3] = (__bf16)f0.w;
            av[4] = (__bf16)f1.x; av[5] = (__bf16)f1.y;
            av[6] = (__bf16)f1.z; av[7] = (__bf16)f1.w;
            bf16x8 bv = *(const bf16x8*)(&W_s[ln][ka]);
            acc = __builtin_amdgcn_mfma_f32_16x16x32_bf16(av, bv, acc, 0, 0, 0);
        }
    }

    // h part: K = 256..1279, h_{t-1} from bf16 ping-pong buffer (zero at t=0)
    if (t > 0) {
        const __bf16* hrow =
            hping + (size_t)((t - 1) & 1) * (BB * HH) + (size_t)brow * HH;
#pragma unroll 8
        for (int k0 = 0; k0 < HH; k0 += 32) {
            int ka = k0 + q * 8;
            bf16x8 av = *(const bf16x8*)(hrow + ka);
            bf16x8 bv = *(const bf16x8*)(&W_s[ln][DD + ka]);
            acc = __builtin_amdgcn_mfma_f32_16x16x32_bf16(av, bv, acc, 0, 0, 0);
        }
    }

    // C[row=(q*4+r)][col=ln] -> LDS so each thread can gather its 4 gates
#pragma unroll
    for (int r = 0; r < 4; ++r)
        gate_s[wave * 16 + q * 4 + r][ln] = acc[r];
    __syncthreads();

    // thread -> (b, jj); packed col n = gate*4 + jj
    const int b2 = tid >> 2;
    const int jj = tid & 3;
    const int j = j0 + jj;
    float iv = gate_s[b2][jj]      + bc[j];
    float fv = gate_s[b2][4 + jj]  + bc[HH + j];
    float gv = gate_s[b2][8 + jj]  + bc[2 * HH + j];
    float ov = gate_s[b2][12 + jj] + bc[3 * HH + j];
    iv = 1.f / (1.f + expf(-iv));
    fv = 1.f / (1.f + expf(-fv));
    gv = 1.f / (1.f + expf(-gv));   // NOTE: reference sigmoids the cell gate too
    ov = 1.f / (1.f + expf(-ov));
    float cc = cst[b2 * HH + j];
    cc = cc * fv + iv * gv;
    cst[b2 * HH + j] = cc;
    float hh = ov * tanhf(cc);
    hs[((size_t)b2 * TT + t) * HH + j] = hh;                         // raw h (fp32)
    hping[(size_t)(t & 1) * (BB * HH) + b2 * HH + j] = (__bf16)hh;   // bf16 for next step
}

// ---------------- output head: out = hs @ Wout^T + bout ----------------
// grid: (D/16, B*T/64); block tile 64 rows x 16 d-cols, K = 1024
__global__ __launch_bounds__(256) void out_gemm_kernel(
    const float* __restrict__ hs,    // (B*T, H) raw fp32
    const __bf16* __restrict__ Wob,  // (D, H) bf16
    const float* __restrict__ bout,  // (D)
    float* __restrict__ out) {       // (B*T, D)
    __shared__ __bf16 Wout_s[16][1032];
    const int tid = threadIdx.x;
    const int d0 = blockIdx.x * 16;
    const int row0 = blockIdx.y * 64;

    for (int ch = tid; ch < 2048; ch += 256) {
        int r = ch >> 7;
        int k = (ch & 127) * 8;
        *(uint4*)(&Wout_s[r][k]) = *(const uint4*)(Wob + (size_t)(d0 + r) * HH + k);
    }
    __syncthreads();

    const int wave = tid >> 6;
    const int lane = tid & 63;
    const int ln = lane & 15;
    const int q = lane >> 4;
    const int row = row0 + wave * 16 + ln;

    const float* arow = hs + (size_t)row * HH;
    floatx4 acc = {0.f, 0.f, 0.f, 0.f};
#pragma unroll 8
    for (int k0 = 0; k0 < HH; k0 += 32) {
        int ka = k0 + q * 8;
        float4 f0 = *(const float4*)(arow + ka);
        float4 f1 = *(const float4*)(arow + ka + 4);
        bf16x8 av;
        av[0] = (__bf16)f0.x; av[1] = (__bf16)f0.y;
        av[2] = (__bf16)f0.z; av[3] = (__bf16)f0.w;
        av[4] = (__bf16)f1.x; av[5] = (__bf16)f1.y;
        av[6] = (__bf16)f1.z; av[7] = (__bf16)f1.w;
        bf16x8 bv = *(const bf16x8*)(&Wout_s[ln][ka]);
        acc = __builtin_amdgcn_mfma_f32_16x16x32_bf16(av, bv, acc, 0, 0, 0);
    }
    float bo = bout[d0 + ln];
    const int orow0 = row0 + wave * 16 + q * 4;
#pragma unroll
    for (int r = 0; r < 4; ++r)
        out[(size_t)(orow0 + r) * DD + d0 + ln] = acc[r] + bo;
}

// ---------------- in-place tanh over hidden region ----------------
__global__ void tanh_inplace_kernel(float* __restrict__ p, size_t n) {
    size_t i = ((size_t)blockIdx.x * blockDim.x + threadIdx.x) * 4;
    size_t stride = (size_t)gridDim.x * blockDim.x * 4;
    for (; i < n; i += stride) {
        float4 v = *(float4*)(p + i);
        v.x = tanhf(v.x); v.y = tanhf(v.y); v.z = tanhf(v.z); v.w = tanhf(v.w);
        *(float4*)(p + i) = v;
    }
}

extern "C" void kernel_launch(void* const* d_in, const int* in_sizes, int n_in,
                              void* d_out, int out_size, void* d_ws, size_t ws_size,
                              hipStream_t stream) {
    const float* x    = (const float*)d_in[0];  // (B,T,D)
    const float* Wx   = (const float*)d_in[1];  // (4H,D)
    const float* bx   = (const float*)d_in[2];  // (4H)
    const float* Wh   = (const float*)d_in[3];  // (4H,H)
    const float* bh   = (const float*)d_in[4];  // (4H)
    const float* Wout = (const float*)d_in[5];  // (D,H)
    const float* bout = (const float*)d_in[6];  // (D)

    float* out = (float*)d_out;                        // (B,T,D)
    float* hidden = out + (size_t)BB * TT * DD;        // (B,T,H): raw h, then tanh'd

    // workspace layout (all 16B aligned), ~11.6 MB total
    char* ws = (char*)d_ws;
    __bf16* Wxb = (__bf16*)(ws);                                   // 2 MB
    __bf16* Whb = (__bf16*)(ws + (size_t)2 * 1024 * 1024);         // 8 MB
    __bf16* Wob = (__bf16*)(ws + (size_t)10 * 1024 * 1024 + 512 * 1024 - 512 * 1024); // = ws+10MB
    // (keep explicit offsets simple:)
    Wob = (__bf16*)(ws + 10485760);                                // 0.5 MB
    float* bc   = (float*)(ws + 11010048);                         // 16 KB
    float* cst  = (float*)(ws + 11026432);                         // 256 KB
    __bf16* hping = (__bf16*)(ws + 11288576);                      // 256 KB

    // weight conversions + init
    cvt_bf16_kernel<<<(GG * DD / 8 + 255) / 256, 256, 0, stream>>>(Wx, Wxb, GG * DD);
    cvt_bf16_kernel<<<(GG * HH / 8 + 255) / 256, 256, 0, stream>>>(Wh, Whb, GG * HH);
    cvt_bf16_kernel<<<(DD * HH / 8 + 255) / 256, 256, 0, stream>>>(Wout, Wob, DD * HH);
    init_misc_kernel<<<(BB * HH + 255) / 256, 256, 0, stream>>>(bx, bh, bc, cst);

    // sequential LSTM
    for (int t = 0; t < TT; ++t) {
        lstm_step_kernel<<<HH / 4, 256, 0, stream>>>(x, Wxb, Whb, bc, cst,
                                                     hidden, hping, t);
    }

    // output head, then tanh the hidden region in place
    out_gemm_kernel<<<dim3(DD / 16, (BB * TT) / 64), 256, 0, stream>>>(
        hidden, Wob, bout, out);
    tanh_inplace_kernel<<<2048, 256, 0, stream>>>(hidden, (size_t)BB * TT * HH);
}